// Round 19
// baseline (136.349 us; speedup 1.0000x reference)
//
#include <hip/hip_runtime.h>

// Problem: B=16, T=4096, D=512, R=256. Output (B,T,R+1) float32.
// build_kt: normalized bf16 K panel, fragment-blocked [b][ks][rt] 1KB tiles.
// nystrom_mfma: 512 thr / 8 waves; block = 8 consecutive TM=16 t-tiles.
//  - Staging via global_load_lds (f32, no VGPR round-trip), double-buffered.
//  - Pipeline: issue tile j+1's 4 DMAs -> s_waitcnt vmcnt(4) -> raw s_barrier
//    -> K-loop(tile j). No __syncthreads anywhere (no vmcnt(0) drains).
//  - LDS stripes: stripe s=ks*2+h holds lane l's z[t0+(l&15)][ks*32+(l>>4)*8
//    +h*4 ..+4) at s*1024 + l*16 -> A ds_read_b128 is lane-consecutive
//    (conflict-free); bf16 cvt via v_cvt_pk_bf16_f32; norms during cvt.
//  - B panel persistent in 32 named VGPR octs (loaded once per block).
//  - Rowsum: intra-wave shfl + LDS atomicAdd + one raw barrier (parity bufs).

typedef float f32x4 __attribute__((ext_vector_type(4)));
typedef short s16x8 __attribute__((ext_vector_type(8)));
typedef unsigned short u16x8 __attribute__((ext_vector_type(8)));

__device__ __forceinline__ unsigned short f2bf(float f) {
    unsigned u = __builtin_bit_cast(unsigned, f);
    return (unsigned short)((u + 0x7FFFu + ((u >> 16) & 1u)) >> 16);
}

__device__ __forceinline__ int load_lm(const void* lms_raw, int idx) {
    const int* l32 = (const int*)lms_raw;
    if (l32[1] == 0) {
        const long long* l64 = (const long long*)lms_raw;
        return (int)l64[idx];
    }
    return l32[idx];
}

__device__ __forceinline__ void scalars(const float* gw, const float* ta,
                                        float& a0, float& a1, float& a2, float& atd) {
    float w0 = gw[0], w1 = gw[1], w2 = gw[2];
    float wm = fmaxf(w0, fmaxf(w1, w2));
    float e0 = __expf(w0 - wm), e1 = __expf(w1 - wm), e2 = __expf(w2 - wm);
    float einv = 1.0f / (e0 + e1 + e2);
    a0 = e0 * einv; a1 = e1 * einv; a2 = e2 * einv;
    float tv = ta[0];
    atd = (tv > 0.0f) ? (tv + log1pf(__expf(-tv))) : log1pf(__expf(tv));
}

// pack 8 f32 -> 8 bf16 (RNE) with v_cvt_pk_bf16_f32
__device__ __forceinline__ s16x8 cvt8(f32x4 a, f32x4 b) {
    union { unsigned int u[4]; s16x8 v; } r;
    asm("v_cvt_pk_bf16_f32 %0, %1, %2" : "=v"(r.u[0]) : "v"(a.x), "v"(a.y));
    asm("v_cvt_pk_bf16_f32 %0, %1, %2" : "=v"(r.u[1]) : "v"(a.z), "v"(a.w));
    asm("v_cvt_pk_bf16_f32 %0, %1, %2" : "=v"(r.u[2]) : "v"(b.x), "v"(b.y));
    asm("v_cvt_pk_bf16_f32 %0, %1, %2" : "=v"(r.u[3]) : "v"(b.z), "v"(b.w));
    return r.v;
}

// async global(f32,16B/lane) -> LDS at (uniform dst + lane*16)
__device__ __forceinline__ void gl16(const float* g, unsigned char* l) {
    __builtin_amdgcn_global_load_lds(
        (const __attribute__((address_space(1))) unsigned int*)g,
        (__attribute__((address_space(3))) unsigned int*)l, 16, 0, 0);
}

// ---------------------------------------------------------------------------
// Kernel 1: normalized K panel, fragment-blocked. One wave per (b, r).
// ---------------------------------------------------------------------------
__global__ void build_kt(const float* __restrict__ z,
                         const void* __restrict__ lms_raw,
                         unsigned char* __restrict__ kb) {
    const int b = blockIdx.x >> 8;
    const int r = blockIdx.x & 255;
    const int L = threadIdx.x;
    const int lm = load_lm(lms_raw, r);

    const f32x4* zrow = (const f32x4*)(z + ((size_t)b * 4096 + (size_t)lm) * 512);
    f32x4 v0 = zrow[L * 2 + 0];
    f32x4 v1 = zrow[L * 2 + 1];
    float ss = v0.x*v0.x + v0.y*v0.y + v0.z*v0.z + v0.w*v0.w
             + v1.x*v1.x + v1.y*v1.y + v1.z*v1.z + v1.w*v1.w;
    #pragma unroll
    for (int off = 32; off >= 1; off >>= 1) ss += __shfl_xor(ss, off, 64);
    float inv = 1.0f / fmaxf(sqrtf(ss), 1e-12f);

    u16x8 o;
    o[0]=f2bf(v0.x*inv); o[1]=f2bf(v0.y*inv); o[2]=f2bf(v0.z*inv); o[3]=f2bf(v0.w*inv);
    o[4]=f2bf(v1.x*inv); o[5]=f2bf(v1.y*inv); o[6]=f2bf(v1.z*inv); o[7]=f2bf(v1.w*inv);

    const int rt = r >> 4;
    const int c  = r & 15;
    const int ks = L >> 2;
    const int g  = L & 3;
    size_t off = (size_t)b * 262144
               + (size_t)(ks * 16 + rt) * 1024 + (size_t)(c * 4 + g) * 16;
    *(u16x8*)(kb + off) = o;
}

// --- macro machinery (all literal indices / token-pasted names) -------------
#define FOREACH_KS(X) X(0) X(1) X(2) X(3) X(4) X(5) X(6) X(7) \
                      X(8) X(9) X(10) X(11) X(12) X(13) X(14) X(15)

#define DECLB(KS) u16x8 Bq##KS##a, Bq##KS##b;
#define LOADB(KS) \
    Bq##KS##a = *(const u16x8*)(kbw + (size_t)((KS) * 16 + rt0 + 0) * 1024); \
    Bq##KS##b = *(const u16x8*)(kbw + (size_t)((KS) * 16 + rt0 + 1) * 1024);

#define KSTEP(KS) { \
    f32x4 a0_ = *(const f32x4*)(qb + (KS) * 2048); \
    f32x4 a1_ = *(const f32x4*)(qb + (KS) * 2048 + 1024); \
    ss = fmaf(a0_.x,a0_.x, fmaf(a0_.y,a0_.y, fmaf(a0_.z,a0_.z, fmaf(a0_.w,a0_.w, ss)))); \
    ss = fmaf(a1_.x,a1_.x, fmaf(a1_.y,a1_.y, fmaf(a1_.z,a1_.z, fmaf(a1_.w,a1_.w, ss)))); \
    s16x8 af_ = cvt8(a0_, a1_); \
    acc0 = __builtin_amdgcn_mfma_f32_16x16x32_bf16(af_, __builtin_bit_cast(s16x8, Bq##KS##a), acc0, 0, 0, 0); \
    acc1 = __builtin_amdgcn_mfma_f32_16x16x32_bf16(af_, __builtin_bit_cast(s16x8, Bq##KS##b), acc1, 0, 0, 0); \
}

// wave w stages its 4 stripes (ks=2w,2w+1 x halves) of tile JT into buffer BUF
#define STAGE(BUF, JT) do { \
    const float* zs_ = z + ((size_t)b * 4096 \
                       + (size_t)(tbase + (JT) * 16 + (lane & 15))) * 512 \
                       + (lane >> 4) * 8; \
    unsigned char* qd_ = &qtile[BUF][4 * w][0]; \
    gl16(zs_ + (2 * w + 0) * 32 + 0, qd_ +    0); \
    gl16(zs_ + (2 * w + 0) * 32 + 4, qd_ + 1024); \
    gl16(zs_ + (2 * w + 1) * 32 + 0, qd_ + 2048); \
    gl16(zs_ + (2 * w + 1) * 32 + 4, qd_ + 3072); \
} while (0)

// ---------------------------------------------------------------------------
// Kernel 2: MFMA main. 512 blocks x 512 thr; block = 8 TM=16 tiles.
// ---------------------------------------------------------------------------
__global__ __launch_bounds__(512, 4) void nystrom_mfma(const float* __restrict__ z,
                                                       const float* __restrict__ gw,
                                                       const float* __restrict__ ta,
                                                       const void* __restrict__ lms_raw,
                                                       const unsigned char* __restrict__ kb,
                                                       float* __restrict__ out) {
    __shared__ unsigned char qtile[2][32][1024];   // 64 KB f32 tile, dbuf
    __shared__ float s_rs[2][16];                  // parity rowsum buffers

    const int tid  = threadIdx.x;
    const int lane = tid & 63;
    const int w    = tid >> 6;                     // wave 0..7

    // XCD swizzle: 512 blocks, bijective (512 % 8 == 0)
    const int wgid  = (blockIdx.x & 7) * 64 + (blockIdx.x >> 3);
    const int b     = wgid >> 5;                   // 32 groups per batch
    const int tbase = (wgid & 31) * 128;           // 8 tiles x 16 rows

    const int c = lane & 15;
    const int g = lane >> 4;

    float sa0, sa1, sa2, alpha_td;
    scalars(gw, ta, sa0, sa1, sa2, alpha_td);
    const float C0 = 0.5f * (sa0 - sa1);

    const unsigned char* kbw = kb + (size_t)b * 262144 + (size_t)(c * 4 + g) * 16;
    const int rt0 = 2 * w;                         // wave w owns cols 32w..32w+32

    // persistent B panel: 32 named register octs, loaded once
    FOREACH_KS(DECLB)
    FOREACH_KS(LOADB)

    // hoisted landmark + decay data (cols fixed per wave across all tiles)
    const int lmv0 = load_lm(lms_raw, 32 * w + c);
    const int lmv1 = load_lm(lms_raw, 32 * w + 16 + c);
    const float elm0 = __expf(alpha_td * (float)lmv0 * (1.0f / 4096.0f));
    const float elm1 = __expf(alpha_td * (float)lmv1 * (1.0f / 4096.0f));
    float eR[4];
    #pragma unroll
    for (int q = 0; q < 4; ++q)
        eR[q] = __expf(-alpha_td * (float)(g * 4 + q) * (1.0f / 4096.0f));

    // zero rowsum parity buffers
    if (tid < 32) s_rs[tid >> 4][tid & 15] = 0.0f;

    // prologue: stage tile 0
    STAGE(0, 0);

    #pragma unroll 1
    for (int j = 0; j < 8; ++j) {
        // issue next tile's DMAs (they fly under this tile's K-loop+epilogue)
        if (j < 7) STAGE((j + 1) & 1, j + 1);

        // tile-j DMAs done (all but the 4 just issued); LDS ops drained
        asm volatile("s_waitcnt vmcnt(4) lgkmcnt(0)" ::: "memory");
        __builtin_amdgcn_sched_barrier(0);
        __builtin_amdgcn_s_barrier();

        const unsigned char* qb = &qtile[j & 1][0][0] + lane * 16;
        f32x4 acc0 = {0, 0, 0, 0}, acc1 = {0, 0, 0, 0};
        float ss = 0.0f;

        FOREACH_KS(KSTEP)

        // row norms: ss has 1/4-row (my g); reduce across g, fetch per D-row
        ss += __shfl_xor(ss, 16, 64);
        ss += __shfl_xor(ss, 32, 64);

        const int t0 = tbase + j * 16;
        const float eAj = __expf(-alpha_td * (float)t0 * (1.0f / 4096.0f));

        float phi0[4], phi1[4], rsum[4];
        #pragma unroll
        for (int q = 0; q < 4; ++q) {
            int drow = g * 4 + q;
            float ssq = __shfl(ss, drow, 64);
            float invn = 1.0f / fmaxf(sqrtf(ssq), 1e-12f);
            int tg = t0 + drow;
            float et = eAj * eR[q];
            float v0 = acc0[q] * invn;
            float v1 = acc1[q] * invn;
            float p0, p1;
            if (lmv0 < tg) {
                float c2 = v0 * v0;
                p0 = (sa0 * fmaf(0.5f, v0, 0.5f) + sa1 * fmaf(1.5f, c2, -0.5f)
                    + sa2 * (v0 * fmaf(2.5f, c2, -1.5f))) * (et * elm0);
            } else p0 = C0;
            if (lmv1 < tg) {
                float c2 = v1 * v1;
                p1 = (sa0 * fmaf(0.5f, v1, 0.5f) + sa1 * fmaf(1.5f, c2, -0.5f)
                    + sa2 * (v1 * fmaf(2.5f, c2, -1.5f))) * (et * elm1);
            } else p1 = C0;
            phi0[q] = p0; phi1[q] = p1;
            float s = p0 + p1;
            s += __shfl_xor(s, 1, 64);
            s += __shfl_xor(s, 2, 64);
            s += __shfl_xor(s, 4, 64);
            s += __shfl_xor(s, 8, 64);
            rsum[q] = s;
        }
        if (c == 0) {
            #pragma unroll
            for (int q = 0; q < 4; ++q)
                atomicAdd(&s_rs[j & 1][g * 4 + q], rsum[q]);
        }

        asm volatile("s_waitcnt lgkmcnt(0)" ::: "memory");
        __builtin_amdgcn_sched_barrier(0);
        __builtin_amdgcn_s_barrier();

        // normalize + store
        #pragma unroll
        for (int q = 0; q < 4; ++q) {
            int drow = g * 4 + q;
            float ri = 1.0f / fmaxf(s_rs[j & 1][drow], 1e-6f);
            size_t obase = ((size_t)b * 4096 + (size_t)(t0 + drow)) * 257
                         + (size_t)(32 * w + c);
            out[obase]      = phi0[q] * ri;
            out[obase + 16] = phi1[q] * ri;
        }
        if (tid < 16)
            out[((size_t)b * 4096 + (size_t)(t0 + tid)) * 257 + 256] = 1.0f;

        // reset the OTHER parity buffer (its reads finished before loop-top
        // barrier of this iter; next writes happen after loop-top barrier j+1)
        if (tid < 16) s_rs[(j & 1) ^ 1][tid] = 0.0f;
    }
}

// ---------------------------------------------------------------------------
extern "C" void kernel_launch(void* const* d_in, const int* in_sizes, int n_in,
                              void* d_out, int out_size, void* d_ws, size_t ws_size,
                              hipStream_t stream) {
    const float* z   = (const float*)d_in[0];
    const float* gw  = (const float*)d_in[1];
    const float* ta  = (const float*)d_in[2];
    const void*  lms = (const void*)d_in[3];
    float* out = (float*)d_out;
    unsigned char* kb = (unsigned char*)d_ws;   // 4 MB fragment-blocked panel

    build_kt<<<16 * 256, 64, 0, stream>>>(z, lms, kb);
    nystrom_mfma<<<512, 512, 0, stream>>>(z, gw, ta, lms, kb, out);
}

// Round 20
// 83.119 us; speedup vs baseline: 1.6404x; 1.6404x over previous
//
#include <hip/hip_runtime.h>

// Problem: B=16, T=4096, D=512, R=256. Output (B,T,R+1) float32.
// build_kt: normalized bf16 K panel, fragment-blocked [b][ks][rt] 1KB tiles.
// nystrom_mfma: grid 256 (1 block/CU), 512 thr / 8 waves; 8 TM=32 t-tiles.
//  - Q staged f32 via global_load_lds (no staging VGPRs), double-buffered
//    64KB tiles in 128KB DYNAMIC LDS. Stripe s=ks*4+rh*2+h: lane l holds
//    z[row rh*16+(l&15)][ks*32+(l>>4)*8+h*4 ..+4) at s*1024+l*16 ->
//    A-reads are lane-consecutive 16B (conflict-free).
//  - Tile top: s_waitcnt vmcnt(8) lgkmcnt(0) + raw s_barrier (counted, never
//    vmcnt(0)); STAGE(j+1) issued AFTER the barrier (no buffer race).
//  - B ring (4 slots x 2 frags, 32 VGPRs) from L2; B is tile-invariant so
//    the ring stays primed across tiles ((KS+4)&15 reload).
//  - bf16 via v_cvt_pk_bf16_f32; row norms accumulated during cvt.

typedef float f32x4 __attribute__((ext_vector_type(4)));
typedef short s16x8 __attribute__((ext_vector_type(8)));
typedef unsigned short u16x8 __attribute__((ext_vector_type(8)));

__device__ __forceinline__ unsigned short f2bf(float f) {
    unsigned u = __builtin_bit_cast(unsigned, f);
    return (unsigned short)((u + 0x7FFFu + ((u >> 16) & 1u)) >> 16);
}

__device__ __forceinline__ int load_lm(const void* lms_raw, int idx) {
    const int* l32 = (const int*)lms_raw;
    if (l32[1] == 0) {
        const long long* l64 = (const long long*)lms_raw;
        return (int)l64[idx];
    }
    return l32[idx];
}

__device__ __forceinline__ void scalars(const float* gw, const float* ta,
                                        float& a0, float& a1, float& a2, float& atd) {
    float w0 = gw[0], w1 = gw[1], w2 = gw[2];
    float wm = fmaxf(w0, fmaxf(w1, w2));
    float e0 = __expf(w0 - wm), e1 = __expf(w1 - wm), e2 = __expf(w2 - wm);
    float einv = 1.0f / (e0 + e1 + e2);
    a0 = e0 * einv; a1 = e1 * einv; a2 = e2 * einv;
    float tv = ta[0];
    atd = (tv > 0.0f) ? (tv + log1pf(__expf(-tv))) : log1pf(__expf(tv));
}

__device__ __forceinline__ s16x8 cvt8(f32x4 a, f32x4 b) {
    union { unsigned int u[4]; s16x8 v; } r;
    asm("v_cvt_pk_bf16_f32 %0, %1, %2" : "=v"(r.u[0]) : "v"(a.x), "v"(a.y));
    asm("v_cvt_pk_bf16_f32 %0, %1, %2" : "=v"(r.u[1]) : "v"(a.z), "v"(a.w));
    asm("v_cvt_pk_bf16_f32 %0, %1, %2" : "=v"(r.u[2]) : "v"(b.x), "v"(b.y));
    asm("v_cvt_pk_bf16_f32 %0, %1, %2" : "=v"(r.u[3]) : "v"(b.z), "v"(b.w));
    return r.v;
}

__device__ __forceinline__ void gl16(const float* g, unsigned char* l) {
    __builtin_amdgcn_global_load_lds(
        (const __attribute__((address_space(1))) unsigned int*)g,
        (__attribute__((address_space(3))) unsigned int*)l, 16, 0, 0);
}

// ---------------------------------------------------------------------------
// Kernel 1: normalized K panel, fragment-blocked. One wave per (b, r).
// ---------------------------------------------------------------------------
__global__ void build_kt(const float* __restrict__ z,
                         const void* __restrict__ lms_raw,
                         unsigned char* __restrict__ kb) {
    const int b = blockIdx.x >> 8;
    const int r = blockIdx.x & 255;
    const int L = threadIdx.x;
    const int lm = load_lm(lms_raw, r);

    const f32x4* zrow = (const f32x4*)(z + ((size_t)b * 4096 + (size_t)lm) * 512);
    f32x4 v0 = zrow[L * 2 + 0];
    f32x4 v1 = zrow[L * 2 + 1];
    float ss = v0.x*v0.x + v0.y*v0.y + v0.z*v0.z + v0.w*v0.w
             + v1.x*v1.x + v1.y*v1.y + v1.z*v1.z + v1.w*v1.w;
    #pragma unroll
    for (int off = 32; off >= 1; off >>= 1) ss += __shfl_xor(ss, off, 64);
    float inv = 1.0f / fmaxf(sqrtf(ss), 1e-12f);

    u16x8 o;
    o[0]=f2bf(v0.x*inv); o[1]=f2bf(v0.y*inv); o[2]=f2bf(v0.z*inv); o[3]=f2bf(v0.w*inv);
    o[4]=f2bf(v1.x*inv); o[5]=f2bf(v1.y*inv); o[6]=f2bf(v1.z*inv); o[7]=f2bf(v1.w*inv);

    const int rt = r >> 4;
    const int c  = r & 15;
    const int ks = L >> 2;
    const int g  = L & 3;
    size_t off = (size_t)b * 262144
               + (size_t)(ks * 16 + rt) * 1024 + (size_t)(c * 4 + g) * 16;
    *(u16x8*)(kb + off) = o;
}

// --- macros (literal indices / token-pasted names) ---------------------------
#define LDB(S, KS) do { \
    B##S##a = *(const u16x8*)(kbw + (size_t)((KS) * 16 + rt0 + 0) * 1024); \
    B##S##b = *(const u16x8*)(kbw + (size_t)((KS) * 16 + rt0 + 1) * 1024); \
} while (0)

#define DOT4(V) fmaf(V.x, V.x, fmaf(V.y, V.y, fmaf(V.z, V.z, V.w * V.w)))

#define KSTEP(KS, S) do { \
    f32x4 a00_ = *(const f32x4*)(qb + ((KS) * 4 + 0) * 1024); \
    f32x4 a01_ = *(const f32x4*)(qb + ((KS) * 4 + 1) * 1024); \
    f32x4 a10_ = *(const f32x4*)(qb + ((KS) * 4 + 2) * 1024); \
    f32x4 a11_ = *(const f32x4*)(qb + ((KS) * 4 + 3) * 1024); \
    ss0 += DOT4(a00_) + DOT4(a01_); \
    ss1 += DOT4(a10_) + DOT4(a11_); \
    s16x8 af0_ = cvt8(a00_, a01_); \
    s16x8 af1_ = cvt8(a10_, a11_); \
    s16x8 ba_ = __builtin_bit_cast(s16x8, B##S##a); \
    s16x8 bb_ = __builtin_bit_cast(s16x8, B##S##b); \
    acc00 = __builtin_amdgcn_mfma_f32_16x16x32_bf16(af0_, ba_, acc00, 0, 0, 0); \
    acc01 = __builtin_amdgcn_mfma_f32_16x16x32_bf16(af0_, bb_, acc01, 0, 0, 0); \
    acc10 = __builtin_amdgcn_mfma_f32_16x16x32_bf16(af1_, ba_, acc10, 0, 0, 0); \
    acc11 = __builtin_amdgcn_mfma_f32_16x16x32_bf16(af1_, bb_, acc11, 0, 0, 0); \
    LDB(S, ((KS) + 4) & 15); \
} while (0)

// wave w stages its 8 stripes (ks=2w,2w+1 x rh x h) of tile JT into buffer BUF
#define STAGE(BUF, JT) do { \
    const float* z0_ = z + ((size_t)b * 4096 \
                      + (size_t)(tbase + (JT) * 32 + (lane & 15))) * 512 \
                      + (lane >> 4) * 8; \
    const float* z1_ = z0_ + 16 * 512; \
    unsigned char* qd_ = qtile + (size_t)(BUF) * 65536 + (size_t)w * 8192; \
    gl16(z0_ + (2 * w + 0) * 32 + 0, qd_ + 0 * 1024); \
    gl16(z0_ + (2 * w + 0) * 32 + 4, qd_ + 1 * 1024); \
    gl16(z1_ + (2 * w + 0) * 32 + 0, qd_ + 2 * 1024); \
    gl16(z1_ + (2 * w + 0) * 32 + 4, qd_ + 3 * 1024); \
    gl16(z0_ + (2 * w + 1) * 32 + 0, qd_ + 4 * 1024); \
    gl16(z0_ + (2 * w + 1) * 32 + 4, qd_ + 5 * 1024); \
    gl16(z1_ + (2 * w + 1) * 32 + 0, qd_ + 6 * 1024); \
    gl16(z1_ + (2 * w + 1) * 32 + 4, qd_ + 7 * 1024); \
} while (0)

// ---------------------------------------------------------------------------
// Kernel 2: MFMA main. 256 blocks x 512 thr; block = 8 TM=32 tiles.
// ---------------------------------------------------------------------------
__global__ __launch_bounds__(512, 2) void nystrom_mfma(const float* __restrict__ z,
                                                       const float* __restrict__ gw,
                                                       const float* __restrict__ ta,
                                                       const void* __restrict__ lms_raw,
                                                       const unsigned char* __restrict__ kb,
                                                       float* __restrict__ out) {
    extern __shared__ unsigned char dynlds[];
    unsigned char* qtile = dynlds;                 // 2 x 64 KB f32 Q tiles
    float* s_rs = (float*)(dynlds + 131072);       // [2][32] parity rowsums

    const int tid  = threadIdx.x;
    const int lane = tid & 63;
    const int w    = tid >> 6;                     // wave 0..7

    // XCD swizzle: 256 blocks, bijective
    const int wgid  = (blockIdx.x & 7) * 32 + (blockIdx.x >> 3);
    const int b     = wgid >> 4;                   // 16 groups per batch
    const int tbase = (wgid & 15) * 256;           // 8 tiles x 32 rows

    const int c = lane & 15;
    const int g = lane >> 4;

    float sa0, sa1, sa2, alpha_td;
    scalars(gw, ta, sa0, sa1, sa2, alpha_td);
    const float C0 = 0.5f * (sa0 - sa1);

    const unsigned char* kbw = kb + (size_t)b * 262144 + (size_t)(c * 4 + g) * 16;
    const int rt0 = 2 * w;

    // hoisted landmark + decay data (cols fixed per wave)
    const int lmv0 = load_lm(lms_raw, 32 * w + c);
    const int lmv1 = load_lm(lms_raw, 32 * w + 16 + c);
    const float elm0 = __expf(alpha_td * (float)lmv0 * (1.0f / 4096.0f));
    const float elm1 = __expf(alpha_td * (float)lmv1 * (1.0f / 4096.0f));
    float eR[4];
    #pragma unroll
    for (int q = 0; q < 4; ++q)
        eR[q] = __expf(-alpha_td * (float)(g * 4 + q) * (1.0f / 4096.0f));
    const float d16 = __expf(-alpha_td * (16.0f / 4096.0f));

    if (tid < 64) s_rs[tid] = 0.0f;

    // prologue: stage tile 0 FIRST (oldest VMEM), then prime the B ring
    STAGE(0, 0);
    asm volatile("" ::: "memory");
    u16x8 B0a, B0b, B1a, B1b, B2a, B2b, B3a, B3b;
    LDB(0, 0); LDB(1, 1); LDB(2, 2); LDB(3, 3);

    #pragma unroll 1
    for (int j = 0; j < 8; ++j) {
        // tile-j DMAs provably retired (>=16 stores issue after each STAGE;
        // in-order vmcnt retire): counted wait, never vmcnt(0).
        asm volatile("s_waitcnt vmcnt(8) lgkmcnt(0)" ::: "memory");
        __builtin_amdgcn_sched_barrier(0);
        __builtin_amdgcn_s_barrier();
        __builtin_amdgcn_sched_barrier(0);

        // issue next tile's DMAs now (buffer (j+1)&1 free: its readers
        // finished before the barrier above); they fly under K-loop j.
        if (j < 7) STAGE((j + 1) & 1, j + 1);

        const unsigned char* qb = qtile + (size_t)(j & 1) * 65536 + (size_t)lane * 16;
        f32x4 acc00 = {0,0,0,0}, acc01 = {0,0,0,0};
        f32x4 acc10 = {0,0,0,0}, acc11 = {0,0,0,0};
        float ss0 = 0.0f, ss1 = 0.0f;

        KSTEP( 0, 0); KSTEP( 1, 1); KSTEP( 2, 2); KSTEP( 3, 3);
        KSTEP( 4, 0); KSTEP( 5, 1); KSTEP( 6, 2); KSTEP( 7, 3);
        KSTEP( 8, 0); KSTEP( 9, 1); KSTEP(10, 2); KSTEP(11, 3);
        KSTEP(12, 0); KSTEP(13, 1); KSTEP(14, 2); KSTEP(15, 3);

        // full row sums of |z|^2: reduce quarter-sums across g
        ss0 += __shfl_xor(ss0, 16, 64);
        ss0 += __shfl_xor(ss0, 32, 64);
        ss1 += __shfl_xor(ss1, 16, 64);
        ss1 += __shfl_xor(ss1, 32, 64);

        const int t0 = tbase + j * 32;
        float eA0 = __expf(-alpha_td * (float)t0 * (1.0f / 4096.0f));
        float eA1 = eA0 * d16;

        float phi[2][2][4];
        float rsum[2][4];
        #pragma unroll
        for (int q = 0; q < 4; ++q) {
            int drow = g * 4 + q;
            float in0 = 1.0f / fmaxf(sqrtf(__shfl(ss0, drow, 64)), 1e-12f);
            float in1 = 1.0f / fmaxf(sqrtf(__shfl(ss1, drow, 64)), 1e-12f);
            #pragma unroll
            for (int tf = 0; tf < 2; ++tf) {
                int tg = t0 + tf * 16 + drow;
                float invn = tf ? in1 : in0;
                float et = (tf ? eA1 : eA0) * eR[q];
                float v0 = (tf ? acc10[q] : acc00[q]) * invn;
                float v1 = (tf ? acc11[q] : acc01[q]) * invn;
                float p0, p1;
                if (lmv0 < tg) {
                    float c2 = v0 * v0;
                    p0 = (sa0 * fmaf(0.5f, v0, 0.5f) + sa1 * fmaf(1.5f, c2, -0.5f)
                        + sa2 * (v0 * fmaf(2.5f, c2, -1.5f))) * (et * elm0);
                } else p0 = C0;
                if (lmv1 < tg) {
                    float c2 = v1 * v1;
                    p1 = (sa0 * fmaf(0.5f, v1, 0.5f) + sa1 * fmaf(1.5f, c2, -0.5f)
                        + sa2 * (v1 * fmaf(2.5f, c2, -1.5f))) * (et * elm1);
                } else p1 = C0;
                phi[tf][0][q] = p0;
                phi[tf][1][q] = p1;
                float s = p0 + p1;
                s += __shfl_xor(s, 1, 64);
                s += __shfl_xor(s, 2, 64);
                s += __shfl_xor(s, 4, 64);
                s += __shfl_xor(s, 8, 64);
                rsum[tf][q] = s;
            }
        }
        if (c == 0) {
            #pragma unroll
            for (int tf = 0; tf < 2; ++tf)
                #pragma unroll
                for (int q = 0; q < 4; ++q)
                    atomicAdd(&s_rs[(j & 1) * 32 + tf * 16 + g * 4 + q],
                              rsum[tf][q]);
        }

        asm volatile("s_waitcnt lgkmcnt(0)" ::: "memory");
        __builtin_amdgcn_sched_barrier(0);
        __builtin_amdgcn_s_barrier();
        __builtin_amdgcn_sched_barrier(0);

        #pragma unroll
        for (int tf = 0; tf < 2; ++tf)
            #pragma unroll
            for (int q = 0; q < 4; ++q) {
                int drow = g * 4 + q;
                float ri = 1.0f / fmaxf(s_rs[(j & 1) * 32 + tf * 16 + drow], 1e-6f);
                size_t obase = ((size_t)b * 4096 + (size_t)(t0 + tf * 16 + drow)) * 257
                             + (size_t)(32 * w + c);
                out[obase]      = phi[tf][0][q] * ri;
                out[obase + 16] = phi[tf][1][q] * ri;
            }
        if (tid < 32)
            out[((size_t)b * 4096 + (size_t)(t0 + tid)) * 257 + 256] = 1.0f;

        // reset the other parity buffer for iter j+1 (ordered by next barrier)
        if (tid < 32) s_rs[(((j & 1) ^ 1)) * 32 + tid] = 0.0f;
    }
}

// ---------------------------------------------------------------------------
extern "C" void kernel_launch(void* const* d_in, const int* in_sizes, int n_in,
                              void* d_out, int out_size, void* d_ws, size_t ws_size,
                              hipStream_t stream) {
    const float* z   = (const float*)d_in[0];
    const float* gw  = (const float*)d_in[1];
    const float* ta  = (const float*)d_in[2];
    const void*  lms = (const void*)d_in[3];
    float* out = (float*)d_out;
    unsigned char* kb = (unsigned char*)d_ws;   // 4 MB fragment-blocked panel

    const int dyn_lds = 131072 + 64 * sizeof(float);   // 128 KB + rowsums
    static bool attr_set = false;   // host-side only; idempotent, not stream state
    if (!attr_set) {
        (void)hipFuncSetAttribute((const void*)nystrom_mfma,
                                  hipFuncAttributeMaxDynamicSharedMemorySize,
                                  dyn_lds);
        attr_set = true;
    }

    build_kt<<<16 * 256, 64, 0, stream>>>(z, lms, kb);
    nystrom_mfma<<<256, 512, dyn_lds, stream>>>(z, gw, ta, lms, kb, out);
}